// Round 2
// baseline (155.754 us; speedup 1.0000x reference)
//
#include <hip/hip_runtime.h>

#define N_RAYS 262144
#define N_SAMPLES 128

// 32 lanes per ray (2 rays per wave); 4 consecutive samples per lane.
// All global loads are aligned float4 (16 B/lane). Exclusive cumprod of
// (1 - alpha + 1e-10) via width-32 wave prefix-product scan.
__global__ __launch_bounds__(256) void volrend_kernel(
    const float* __restrict__ sigma,
    const float* __restrict__ colors,
    const float* __restrict__ z_vals,
    const float* __restrict__ rays_d,
    float* __restrict__ out)
{
    const int tid  = blockIdx.x * 256 + threadIdx.x;
    const int ray  = tid >> 5;          // 32 threads per ray
    const int l    = threadIdx.x & 31;  // lane within the ray group

    // ---- loads ----
    const float dx = rays_d[ray * 3 + 0];
    const float dy = rays_d[ray * 3 + 1];
    const float dz = rays_d[ray * 3 + 2];
    const float nrm = sqrtf(dx * dx + dy * dy + dz * dz);

    const int s0 = l * 4;
    const size_t rbase = (size_t)ray * N_SAMPLES;
    const float4 zv = *reinterpret_cast<const float4*>(z_vals + rbase + s0);
    const float4 sg = *reinterpret_cast<const float4*>(sigma  + rbase + s0);
    const float* cbase = colors + rbase * 3 + (size_t)s0 * 3;   // 48 B/lane, 16B-aligned
    const float4 c0 = *reinterpret_cast<const float4*>(cbase + 0);
    const float4 c1 = *reinterpret_cast<const float4*>(cbase + 4);
    const float4 c2 = *reinterpret_cast<const float4*>(cbase + 8);
    // sample s0   : (c0.x, c0.y, c0.z)
    // sample s0+1 : (c0.w, c1.x, c1.y)
    // sample s0+2 : (c1.z, c1.w, c2.x)
    // sample s0+3 : (c2.y, c2.z, c2.w)

    // ---- dists ----
    const float z_next = __shfl_down(zv.x, 1, 32);   // z[s0+4] (within 32-lane segment)
    const float dist0 = (zv.y - zv.x) * nrm;
    const float dist1 = (zv.z - zv.y) * nrm;
    const float dist2 = (zv.w - zv.z) * nrm;
    const float dist3 = (l == 31) ? (1e10f * nrm) : (z_next - zv.w) * nrm;

    // ---- alpha / survival ----
    const float e0 = __expf(-fmaxf(sg.x, 0.0f) * dist0);
    const float e1 = __expf(-fmaxf(sg.y, 0.0f) * dist1);
    const float e2 = __expf(-fmaxf(sg.z, 0.0f) * dist2);
    const float e3 = __expf(-fmaxf(sg.w, 0.0f) * dist3);
    const float alpha0 = 1.0f - e0, alpha1 = 1.0f - e1;
    const float alpha2 = 1.0f - e2, alpha3 = 1.0f - e3;
    const float a0 = e0 + 1e-10f, a1 = e1 + 1e-10f;
    const float a2 = e2 + 1e-10f, a3 = e3 + 1e-10f;

    // ---- exclusive prefix product over 128 samples (4/lane, 32 lanes) ----
    float scan = (a0 * a1) * (a2 * a3);
    #pragma unroll
    for (int off = 1; off < 32; off <<= 1) {
        const float n = __shfl_up(scan, off, 32);
        if (l >= off) scan *= n;
    }
    float excl = __shfl_up(scan, 1, 32);
    if (l == 0) excl = 1.0f;

    const float T0 = excl;
    const float T1 = T0 * a0;
    const float T2 = T1 * a1;
    const float T3 = T2 * a2;
    const float w0 = T0 * alpha0;
    const float w1 = T1 * alpha1;
    const float w2 = T2 * alpha2;
    const float w3 = T3 * alpha3;

    // ---- reductions (width-32 butterflies) ----
    float acc   = (w0 + w1) + (w2 + w3);
    float depth = (w0 * zv.x + w1 * zv.y) + (w2 * zv.z + w3 * zv.w);
    float cr    = (w0 * c0.x + w1 * c0.w) + (w2 * c1.z + w3 * c2.y);
    float cg    = (w0 * c0.y + w1 * c1.x) + (w2 * c1.w + w3 * c2.z);
    float cb    = (w0 * c0.z + w1 * c1.y) + (w2 * c2.x + w3 * c2.w);
    #pragma unroll
    for (int off = 16; off; off >>= 1) {
        acc   += __shfl_xor(acc,   off, 32);
        depth += __shfl_xor(depth, off, 32);
        cr    += __shfl_xor(cr,    off, 32);
        cg    += __shfl_xor(cg,    off, 32);
        cb    += __shfl_xor(cb,    off, 32);
    }

    // ---- writes ----
    // out layout (flat, f32): rgb[R,3] | weights[R,128] | depth[R] | disp[R] | acc[R]
    const size_t R = N_RAYS;
    float* wout = out + 3 * R + rbase + s0;
    *reinterpret_cast<float4*>(wout) = make_float4(w0, w1, w2, w3);

    if (l == 0) {
        out[(size_t)ray * 3 + 0] = cr;
        out[(size_t)ray * 3 + 1] = cg;
        out[(size_t)ray * 3 + 2] = cb;
        out[131 * R + ray] = depth;
        out[132 * R + ray] = 1.0f / fmaxf(1e-10f, depth / acc);
        out[133 * R + ray] = acc;
    }
}

extern "C" void kernel_launch(void* const* d_in, const int* in_sizes, int n_in,
                              void* d_out, int out_size, void* d_ws, size_t ws_size,
                              hipStream_t stream) {
    const float* sigma  = (const float*)d_in[0];
    const float* colors = (const float*)d_in[1];
    const float* z_vals = (const float*)d_in[2];
    const float* rays_d = (const float*)d_in[3];
    float* out = (float*)d_out;

    dim3 block(256);                           // 8 rays per block
    dim3 grid(N_RAYS / 8);                     // 32768 blocks
    volrend_kernel<<<grid, block, 0, stream>>>(sigma, colors, z_vals, rays_d, out);
}

// Round 3
// 142.181 us; speedup vs baseline: 1.0955x; 1.0955x over previous
//
#include <hip/hip_runtime.h>

#define N_RAYS 262144
#define N_SAMPLES 128

typedef float vf2 __attribute__((ext_vector_type(2)));

// One wave (64 lanes) per ray; 2 consecutive samples per lane.
// Non-temporal loads for single-touch streams; coalesced block epilogue.
__global__ __launch_bounds__(256) void volrend_kernel(
    const float* __restrict__ sigma,
    const float* __restrict__ colors,
    const float* __restrict__ z_vals,
    const float* __restrict__ rays_d,
    float* __restrict__ out)
{
    const int wid  = threadIdx.x >> 6;   // wave in block: 0..3
    const int lane = threadIdx.x & 63;
    const int ray  = blockIdx.x * 4 + wid;

    __shared__ float sred[4][6];         // per-ray: cr,cg,cb,depth,disp,acc

    // ---- ray direction norm (wave-uniform broadcast load) ----
    const float dx = rays_d[ray * 3 + 0];
    const float dy = rays_d[ray * 3 + 1];
    const float dz = rays_d[ray * 3 + 2];
    const float nrm = sqrtf(dx * dx + dy * dy + dz * dz);

    // ---- loads ----
    const int s0 = lane * 2;
    const size_t rbase = (size_t)ray * N_SAMPLES;
    const vf2 zv = __builtin_nontemporal_load(
        reinterpret_cast<const vf2*>(z_vals + rbase + s0));
    const vf2 sg = __builtin_nontemporal_load(
        reinterpret_cast<const vf2*>(sigma + rbase + s0));
    const float* cbase = colors + rbase * 3 + (size_t)s0 * 3;
    const vf2 c01 = *reinterpret_cast<const vf2*>(cbase + 0);
    const vf2 c23 = *reinterpret_cast<const vf2*>(cbase + 2);
    const vf2 c45 = *reinterpret_cast<const vf2*>(cbase + 4);
    // sample s0   : color (c01.x, c01.y, c23.x)
    // sample s0+1 : color (c23.y, c45.x, c45.y)

    // ---- dists ----
    const float z_next = __shfl_down(zv.x, 1, 64);       // z[s0+2]
    const float dist0 = (zv.y - zv.x) * nrm;
    const float dist1 = (lane == 63) ? (1e10f * nrm) : (z_next - zv.y) * nrm;

    // ---- alpha / survival ----
    const float e0 = __expf(-fmaxf(sg.x, 0.0f) * dist0);
    const float e1 = __expf(-fmaxf(sg.y, 0.0f) * dist1);
    const float alpha0 = 1.0f - e0;
    const float alpha1 = 1.0f - e1;
    const float a0 = e0 + 1e-10f;   // (1 - alpha) + 1e-10
    const float a1 = e1 + 1e-10f;

    // ---- exclusive prefix product over 128 samples (2/lane) ----
    float scan = a0 * a1;
    #pragma unroll
    for (int off = 1; off < 64; off <<= 1) {
        const float n = __shfl_up(scan, off, 64);
        if (lane >= off) scan *= n;
    }
    float excl = __shfl_up(scan, 1, 64);
    if (lane == 0) excl = 1.0f;

    const float w0 = excl * alpha0;
    const float w1 = excl * a0 * alpha1;

    // ---- weights store (early, non-temporal, coalesced 512B/wave) ----
    const size_t R = N_RAYS;
    vf2 wv; wv.x = w0; wv.y = w1;
    __builtin_nontemporal_store(
        wv, reinterpret_cast<vf2*>(out + 3 * R + rbase + s0));

    // ---- reductions ----
    float acc   = w0 + w1;
    float depth = w0 * zv.x  + w1 * zv.y;
    float cr    = w0 * c01.x + w1 * c23.y;
    float cg    = w0 * c01.y + w1 * c45.x;
    float cb    = w0 * c23.x + w1 * c45.y;
    #pragma unroll
    for (int off = 32; off; off >>= 1) {
        acc   += __shfl_xor(acc,   off, 64);
        depth += __shfl_xor(depth, off, 64);
        cr    += __shfl_xor(cr,    off, 64);
        cg    += __shfl_xor(cg,    off, 64);
        cb    += __shfl_xor(cb,    off, 64);
    }

    if (lane == 0) {
        sred[wid][0] = cr;
        sred[wid][1] = cg;
        sred[wid][2] = cb;
        sred[wid][3] = depth;
        sred[wid][4] = 1.0f / fmaxf(1e-10f, depth / acc);
        sred[wid][5] = acc;
    }
    __syncthreads();

    // ---- coalesced epilogue: one multi-lane store per output segment ----
    // out layout (flat, f32): rgb[R,3] | weights[R,128] | depth[R] | disp[R] | acc[R]
    const int t = threadIdx.x;
    if (t < 12) {                       // rgb: 12 consecutive floats per block
        out[(size_t)blockIdx.x * 12 + t] = sred[t / 3][t % 3];
    } else if (t < 16) {                // depth: 4 consecutive floats
        out[131 * R + (size_t)blockIdx.x * 4 + (t - 12)] = sred[t - 12][3];
    } else if (t < 20) {                // disp
        out[132 * R + (size_t)blockIdx.x * 4 + (t - 16)] = sred[t - 16][4];
    } else if (t < 24) {                // acc
        out[133 * R + (size_t)blockIdx.x * 4 + (t - 20)] = sred[t - 20][5];
    }
}

extern "C" void kernel_launch(void* const* d_in, const int* in_sizes, int n_in,
                              void* d_out, int out_size, void* d_ws, size_t ws_size,
                              hipStream_t stream) {
    const float* sigma  = (const float*)d_in[0];
    const float* colors = (const float*)d_in[1];
    const float* z_vals = (const float*)d_in[2];
    const float* rays_d = (const float*)d_in[3];
    float* out = (float*)d_out;

    dim3 block(256);                 // 4 waves = 4 rays per block
    dim3 grid(N_RAYS / 4);           // 65536 blocks
    volrend_kernel<<<grid, block, 0, stream>>>(sigma, colors, z_vals, rays_d, out);
}